// Round 8
// baseline (3306.257 us; speedup 1.0000x reference)
//
#include <hip/hip_runtime.h>

typedef unsigned short u16;
typedef __attribute__((ext_vector_type(8))) short short8_t;
typedef __attribute__((ext_vector_type(4))) float f32x4_t;
typedef __attribute__((ext_vector_type(16))) float f32x16_t;
typedef __attribute__((ext_vector_type(4))) unsigned u32x4_t;

#define NWG 128
#define SMEM_RECUR (82 * 1024)

// ---------------- helpers ----------------
__device__ __forceinline__ u16 f2bf(float f) {
  union { float f; unsigned u; } v; v.f = f;
  unsigned r = v.u + 0x7fffu + ((v.u >> 16) & 1u);  // RNE
  return (u16)(r >> 16);
}

typedef __attribute__((address_space(1))) const void gas_t;
typedef __attribute__((address_space(3))) void las_t;
__device__ __forceinline__ void gl16(const void* g, void* l) {
  __builtin_amdgcn_global_load_lds((gas_t*)g, (las_t*)l, 16, 0, 0);
}

// chunk tag check: 1 if ANY word's bit31 != expected parity
__device__ __forceinline__ unsigned badchunk(u32x4_t c, unsigned p31) {
  return ((c.x ^ p31) | (c.y ^ p31) | (c.z ^ p31) | (c.w ^ p31)) >> 31;
}
// pack 8 tagged u32 (bf16 in low16) -> short8 of bf16
__device__ __forceinline__ short8_t pack8(u32x4_t a, u32x4_t b) {
  union { unsigned u[4]; short8_t s; } v;
  v.u[0] = (a.x & 0xFFFFu) | (a.y << 16);
  v.u[1] = (a.z & 0xFFFFu) | (a.w << 16);
  v.u[2] = (b.x & 0xFFFFu) | (b.y << 16);
  v.u[3] = (b.z & 0xFFFFu) | (b.w << 16);
  return v.s;
}

// ---------------- prep (round-0 exact + tagged hbw mirror) ----------------
__global__ void prep_kernel(const float* __restrict__ inputo, const float* __restrict__ attn,
                            const float* __restrict__ init_hx,
                            u16* __restrict__ xb, u16* __restrict__ hb, unsigned* __restrict__ hbw,
                            unsigned* __restrict__ flags) {
  int i = blockIdx.x * blockDim.x + threadIdx.x;
  int nthr = gridDim.x * blockDim.x;
  if (i < NWG * 16) flags[i] = 0u;
  for (int j = i; j < 32 * 1024; j += nthr) {
    hb[j] = f2bf(init_hx[j & 1023]);
    hbw[j] = 0x80000000u | (unsigned)f2bf(init_hx[j & 1023]);  // h(-1): tag=1
  }
  for (long j = i; j < (long)8192 * 2048; j += nthr) {
    long r = j >> 11; int k = (int)(j & 2047);
    float v = (k < 1024) ? inputo[(r << 10) + k] : attn[(r << 10) + (k - 1024)];
    xb[j] = f2bf(v);
  }
}

// ---------------- W transpose->bf16 (round-0 exact) ----------------
__global__ void transw_kernel(const float* __restrict__ W, u16* __restrict__ WbT) {
  __shared__ float tile[64][65];
  int kt = blockIdx.x;
  int nt = blockIdx.y;
  int t = threadIdx.x;
  int r = t >> 6, c = t & 63;
#pragma unroll
  for (int p = 0; p < 16; p++) {
    int k = (kt << 6) + (p << 2) + r;
    tile[(p << 2) + r][c] = W[(long)k * 4096 + (nt << 6) + c];
  }
  __syncthreads();
#pragma unroll
  for (int p = 0; p < 16; p++) {
    int n = (nt << 6) + (p << 2) + r;
    WbT[(long)n * 3072 + (kt << 6) + c] = f2bf(tile[c][(p << 2) + r]);
  }
}

// ---------------- Gx GEMM (round-0 exact) ----------------
__global__ __launch_bounds__(256) void gemmx_kernel(const u16* __restrict__ xb, const u16* __restrict__ WbT,
                                                    const float* __restrict__ bias, float* __restrict__ Gx) {
  __shared__ __align__(16) char sA[128 * 64 * 2];
  __shared__ __align__(16) char sB[128 * 64 * 2];
  int tid = threadIdx.x, lane = tid & 63, wave = tid >> 6;
  int m0 = blockIdx.y << 7, n0 = blockIdx.x << 7;
  int mi2 = wave >> 1, ni2 = wave & 1;
  const char* xbb = (const char*)xb;
  const char* wbb = (const char*)WbT;
  f32x4_t acc[4][4];
#pragma unroll
  for (int i = 0; i < 4; i++)
#pragma unroll
    for (int j = 0; j < 4; j++)
      acc[i][j] = (f32x4_t){0.f, 0.f, 0.f, 0.f};

  for (int kt = 0; kt < 32; kt++) {
    int k0b = kt << 7;
#pragma unroll
    for (int cc = 0; cc < 4; cc++) {
      int L = (cc << 12) + (tid << 4);
      int row = L >> 7, colb = L & 127;
      gl16(xbb + (long)(m0 + row) * 4096 + k0b + (colb ^ ((row & 7) << 4)),
           sA + (cc << 12) + (wave << 10));
      gl16(wbb + (long)(n0 + row) * 6144 + k0b + (colb ^ ((row & 7) << 4)),
           sB + (cc << 12) + (wave << 10));
    }
    __syncthreads();
#pragma unroll
    for (int ks = 0; ks < 2; ks++) {
      short8_t af[4], bf[4];
#pragma unroll
      for (int i = 0; i < 4; i++) {
        int m = (mi2 << 6) + (i << 4) + (lane & 15);
        int kb = (ks << 6) + ((lane >> 4) << 4);
        af[i] = *(const short8_t*)(sA + (m << 7) + (kb ^ ((m & 7) << 4)));
        int n = (ni2 << 6) + (i << 4) + (lane & 15);
        bf[i] = *(const short8_t*)(sB + (n << 7) + (kb ^ ((n & 7) << 4)));
      }
#pragma unroll
      for (int i = 0; i < 4; i++)
#pragma unroll
        for (int j = 0; j < 4; j++)
          acc[i][j] = __builtin_amdgcn_mfma_f32_16x16x32_bf16(af[i], bf[j], acc[i][j], 0, 0, 0);
    }
    __syncthreads();
  }
#pragma unroll
  for (int j = 0; j < 4; j++) {
    int col = n0 + (ni2 << 6) + (j << 4) + (lane & 15);
    float bval = bias[col];
#pragma unroll
    for (int i = 0; i < 4; i++) {
      int rb = m0 + (mi2 << 6) + (i << 4) + ((lane >> 4) << 2);
#pragma unroll
      for (int r = 0; r < 4; r++)
        Gx[(long)(rb + r) * 4096 + col] = acc[i][j][r] + bval;
    }
  }
}

#define TIE16(op, a) asm volatile(op : \
  "+v"((a)[0]), "+v"((a)[1]), "+v"((a)[2]), "+v"((a)[3]), \
  "+v"((a)[4]), "+v"((a)[5]), "+v"((a)[6]), "+v"((a)[7]), \
  "+v"((a)[8]), "+v"((a)[9]), "+v"((a)[10]), "+v"((a)[11]), \
  "+v"((a)[12]), "+v"((a)[13]), "+v"((a)[14]), "+v"((a)[15]) :: "memory")

// ---------------- poll: early-exit masked + sleep (proven round-0 code) ----------------
__device__ __forceinline__ void poll_flags(unsigned* flags, int tid, unsigned ep) {
  if (tid < NWG) {
    unsigned* fp = &flags[tid << 4];
    bool done = __hip_atomic_load(fp, __ATOMIC_RELAXED, __HIP_MEMORY_SCOPE_AGENT) >= ep;
    while (!__all(done)) {
      __builtin_amdgcn_s_sleep(1);
      if (!done)
        done = __hip_atomic_load(fp, __ATOMIC_RELAXED, __HIP_MEMORY_SCOPE_AGENT) >= ep;
    }
  }
  __syncthreads();
}

// ---------------- persistent recurrent kernel ----------------
// REGULAR (non-cooperative) launch: co-residency by capacity (1 WG/CU via 82KB LDS +
// launch_bounds(256,1), NWG=128 <= 256 CUs). Round-0 two-barrier protocol intact.
// h exchange = tagged-only, low-VGPR two-batch loads; tag violations -> +64 diag channel.
__global__ __launch_bounds__(256, 1) void recur_kernel(
    const float* __restrict__ inputo, const u16* __restrict__ WbT, const float* __restrict__ Gx,
    const float* __restrict__ ln_g, const float* __restrict__ ln_b, const float* __restrict__ init_cx,
    u16* __restrict__ hb, unsigned* __restrict__ hbw,
    unsigned long long* __restrict__ partials, unsigned* __restrict__ flags,
    float* __restrict__ dump, float* __restrict__ out) {
  extern __shared__ __align__(16) char smem[];
  char* Wh = smem;
  float* accb = (float*)(smem + 65536);
  int wg = blockIdx.x, tid = threadIdx.x, lane = tid & 63, wave = tid >> 6;
  int jb = wg << 3;
  int gq = tid & 7;
  int b = tid >> 3;
  int gj = jb + gq;
  float lng0 = ln_g[gj], lng1 = ln_g[1024 + gj], lng2 = ln_g[2048 + gj], lng3 = ln_g[3072 + gj];
  float lnb0 = ln_b[gj], lnb1 = ln_b[1024 + gj], lnb2 = ln_b[2048 + gj], lnb3 = ln_b[3072 + gj];
  float creg = init_cx[gj];
  (void)hb;

  const char* wbb = (const char*)WbT;
  const char* hwb = (const char*)hbw;

  // stage W_h slice once (swizzled image)
#pragma unroll
  for (int cc = 0; cc < 16; cc++) {
    int L = (cc << 12) + (tid << 4);
    int row = L >> 11, colb = L & 2047;
    int n = ((row >> 3) << 10) + jb + (row & 7);
    gl16(wbb + (long)n * 6144 + 4096 + (colb ^ ((row & 15) << 4)),
         Wh + (cc << 12) + (wave << 10));
  }
  asm volatile("s_waitcnt vmcnt(0)" ::: "memory");
  __syncthreads();

  int m = lane & 31, g2 = lane >> 5;
  int cs = gq << 2, gate = cs >> 3, joff = cs & 7;
  long orow = (long)b << 8;
  float out_prev = 0.f;
  unsigned diag = 0u;

#pragma unroll 1
  for (int t = 0; t < 256; t++) {
    unsigned pin31 = (unsigned)(~t & 1) << 31;   // tag of h(t-1)
    unsigned pout31 = (unsigned)(t & 1) << 31;   // tag of this step's h

    // ---- issue: out store (prev step), tagged batch-1 (ks 0..7), Gx, inputo
    {
      float* outp = (t > 0) ? (out + ((orow + t - 1) << 10) + gj) : (dump + tid);
      asm volatile("global_store_dword %0, %1, off" :: "v"(outp), "v"(out_prev) : "memory");
    }
    u32x4_t c[16];
#pragma unroll
    for (int ks = 0; ks < 8; ks++) {
      int kb = (wave << 9) + (ks << 5) + (g2 << 4);
      const char* p = hwb + (m << 12) + (kb << 1);
      asm volatile("global_load_dwordx4 %0, %1, off sc0 sc1" : "=v"(c[2 * ks]) : "v"(p));
      asm volatile("global_load_dwordx4 %0, %1, off sc0 sc1" : "=v"(c[2 * ks + 1]) : "v"(p + 16));
    }
    f32x4_t gxv;
    {
      const float* gp = Gx + (((orow + t) << 12)) + (gate << 10) + jb + joff;
      asm volatile("global_load_dwordx4 %0, %1, off" : "=v"(gxv) : "v"(gp));
    }
    float inp;
    {
      const float* ip = inputo + ((orow + t) << 10) + gj;
      asm volatile("global_load_dword %0, %1, off" : "=v"(inp) : "v"(ip));
    }
    // batch1 retired (gxv, inp newest, still in flight)
    TIE16("s_waitcnt vmcnt(2)", c);
    __builtin_amdgcn_sched_barrier(0);

    short8_t av[16];
#pragma unroll
    for (int ks = 0; ks < 8; ks++) {
      diag |= badchunk(c[2 * ks], pin31) | badchunk(c[2 * ks + 1], pin31);
      av[ks] = pack8(c[2 * ks], c[2 * ks + 1]);
    }
    // ---- tagged batch-2 (ks 8..15), registers reused; full drain (FIFO semantics)
#pragma unroll
    for (int ks = 8; ks < 16; ks++) {
      int kb = (wave << 9) + (ks << 5) + (g2 << 4);
      const char* p = hwb + (m << 12) + (kb << 1);
      asm volatile("global_load_dwordx4 %0, %1, off sc0 sc1" : "=v"(c[2 * (ks - 8)]) : "v"(p));
      asm volatile("global_load_dwordx4 %0, %1, off sc0 sc1" : "=v"(c[2 * (ks - 8) + 1]) : "v"(p + 16));
    }
    TIE16("s_waitcnt vmcnt(0)", c);
    asm volatile("" : "+v"(gxv), "+v"(inp));
    __builtin_amdgcn_sched_barrier(0);
#pragma unroll
    for (int ks = 8; ks < 16; ks++) {
      diag |= badchunk(c[2 * (ks - 8)], pin31) | badchunk(c[2 * (ks - 8) + 1], pin31);
      av[ks] = pack8(c[2 * (ks - 8)], c[2 * (ks - 8) + 1]);
    }

    // ---- GEMM, dual accumulator chains (round-0 exact)
    f32x16_t acc0 = {0.f,0.f,0.f,0.f,0.f,0.f,0.f,0.f,0.f,0.f,0.f,0.f,0.f,0.f,0.f,0.f};
    f32x16_t acc1 = {0.f,0.f,0.f,0.f,0.f,0.f,0.f,0.f,0.f,0.f,0.f,0.f,0.f,0.f,0.f,0.f};
#pragma unroll
    for (int ks = 0; ks < 8; ks++) {
      int kb0 = (wave << 9) + ((2 * ks) << 5) + (g2 << 4);
      int kb1 = (wave << 9) + ((2 * ks + 1) << 5) + (g2 << 4);
      short8_t bv0 = *(const short8_t*)(Wh + (m << 11) + (kb0 ^ ((m & 15) << 4)));
      short8_t bv1 = *(const short8_t*)(Wh + (m << 11) + (kb1 ^ ((m & 15) << 4)));
      acc0 = __builtin_amdgcn_mfma_f32_32x32x16_bf16(av[2 * ks], bv0, acc0, 0, 0, 0);
      acc1 = __builtin_amdgcn_mfma_f32_32x32x16_bf16(av[2 * ks + 1], bv1, acc1, 0, 0, 0);
    }
#pragma unroll
    for (int r = 0; r < 16; r++) acc0[r] += acc1[r];
    // C layout 32x32: col = lane&31, row = (r&3) + 8*(r>>2) + 4*(lane>>5)
#pragma unroll
    for (int r = 0; r < 16; r++) {
      int row = (r & 3) + ((r >> 2) << 3) + (g2 << 2);
      accb[(wave << 10) + (row << 5) + m] = acc0[r];
    }
    __syncthreads();

    // ---- reduce 4 K-partials + Gx (vectorized), LN stats partials
    int e0 = (b << 5) + cs;
    f32x4_t p0 = *(const f32x4_t*)(accb + e0);
    f32x4_t p1 = *(const f32x4_t*)(accb + 1024 + e0);
    f32x4_t p2 = *(const f32x4_t*)(accb + 2048 + e0);
    f32x4_t p3 = *(const f32x4_t*)(accb + 3072 + e0);
    f32x4_t gv;
#pragma unroll
    for (int u = 0; u < 4; u++) gv[u] = p0[u] + p1[u] + p2[u] + p3[u] + gxv[u];
    *(f32x4_t*)(accb + e0) = gv;
    float s = gv[0] + gv[1] + gv[2] + gv[3];
    float ss = gv[0]*gv[0] + gv[1]*gv[1] + gv[2]*gv[2] + gv[3]*gv[3];
#pragma unroll
    for (int mk = 1; mk < 8; mk <<= 1) { s += __shfl_xor(s, mk, 64); ss += __shfl_xor(ss, mk, 64); }
    if (gq == 0) {
      union { unsigned long long u; float2 f; } pv; pv.f = make_float2(s, ss);
      __hip_atomic_store(&partials[(b << 7) + wg], pv.u, __ATOMIC_RELAXED, __HIP_MEMORY_SCOPE_AGENT);
    }

    // ---- barrier 1: partials ready (round-0 exact)
    unsigned ep1 = (unsigned)(2 * t + 1);
    asm volatile("s_waitcnt vmcnt(0)" : "+v"(inp) :: "memory");
    __syncthreads();
    if (tid == 0) __hip_atomic_store(&flags[wg << 4], ep1, __ATOMIC_RELAXED, __HIP_MEMORY_SCOPE_AGENT);
    poll_flags(flags, tid, ep1);

    // ---- LN stats finalize
    float s2 = 0.f, ss2 = 0.f;
    {
      const unsigned long long* pp = partials + (b << 7) + (gq << 4);
#pragma unroll
      for (int i2 = 0; i2 < 16; i2++) {
        union { unsigned long long u; float2 f; } pv;
        pv.u = __hip_atomic_load(&pp[i2], __ATOMIC_RELAXED, __HIP_MEMORY_SCOPE_AGENT);
        s2 += pv.f.x; ss2 += pv.f.y;
      }
#pragma unroll
      for (int mk = 1; mk < 8; mk <<= 1) { s2 += __shfl_xor(s2, mk, 64); ss2 += __shfl_xor(ss2, mk, 64); }
    }
    float mean = s2 * (1.f / 4096.f);
    float var = ss2 * (1.f / 4096.f) - mean * mean;
    float rstd = rsqrtf(var + 1e-5f);

    // ---- gates + cell update; tagged h store
    {
      float g0 = accb[(b << 5) + gq];
      float g1 = accb[(b << 5) + 8 + gq];
      float g2v = accb[(b << 5) + 16 + gq];
      float g3 = accb[(b << 5) + 24 + gq];
      g0 = (g0 - mean) * rstd * lng0 + lnb0;
      g1 = (g1 - mean) * rstd * lng1 + lnb1;
      g2v = (g2v - mean) * rstd * lng2 + lnb2;
      g3 = (g3 - mean) * rstd * lng3 + lnb3;
      float iv = 1.f / (1.f + __expf(-g0));
      float fv = 1.f / (1.f + __expf(-g1));
      float ov = 1.f / (1.f + __expf(-g2v));
      float e2 = __expf(2.f * g3);
      float hv = (e2 - 1.f) / (e2 + 1.f);
      creg = fv * creg + iv * hv;
      float h = ov * creg;
      out_prev = h + inp + (diag ? 64.0f : 0.0f);   // diag signature channel
      __hip_atomic_store(&hbw[(b << 10) + gj], pout31 | (unsigned)f2bf(h),
                         __ATOMIC_RELAXED, __HIP_MEMORY_SCOPE_AGENT);
    }

    // ---- barrier 2: h ready (round-0 exact)
    unsigned ep2 = ep1 + 1;
    asm volatile("s_waitcnt vmcnt(0)" ::: "memory");
    __syncthreads();
    if (tid == 0) __hip_atomic_store(&flags[wg << 4], ep2, __ATOMIC_RELAXED, __HIP_MEMORY_SCOPE_AGENT);
    poll_flags(flags, tid, ep2);
  }
  out[((orow + 255) << 10) + gj] = out_prev;
}

__global__ void sentinel_kernel(float* out) { out[0] = 1.2345678e7f; }
__global__ void canary_kernel(float* out) { out[1] = 7.6543210e6f; }
__global__ void canary2_kernel(float* out) { out[2] = 3.4567890e6f; }

extern "C" void kernel_launch(void* const* d_in, const int* in_sizes, int n_in,
                              void* d_out, int out_size, void* d_ws, size_t ws_size,
                              hipStream_t stream) {
  (void)in_sizes; (void)n_in; (void)out_size;
  const float* inputo  = (const float*)d_in[0];
  const float* attn    = (const float*)d_in[1];
  const float* W       = (const float*)d_in[2];
  const float* bias    = (const float*)d_in[3];
  const float* ln_g    = (const float*)d_in[4];
  const float* ln_b    = (const float*)d_in[5];
  const float* init_hx = (const float*)d_in[6];
  const float* init_cx = (const float*)d_in[7];
  float* out = (float*)d_out;
  char* ws = (char*)d_ws;

  const size_t OFF_XB   = 0;          // 8192*2048*2  = 33554432
  const size_t OFF_WBT  = 33554432;   // 4096*3072*2  = 25165824
  const size_t OFF_GX   = 58720256;   // 8192*4096*4  = 134217728
  const size_t OFF_HB   = 192937984;  // 32*1024*2    = 65536
  const size_t OFF_PART = 193003520;  // 32*128*8     = 32768
  const size_t OFF_FLAG = 193036288;  // 128*16*4     = 8192
  const size_t OFF_DUMP = 193044480;  // 1024 bytes
  const size_t OFF_HBW  = 193045504;  // 32*1024*4    = 131072 (tagged h)
  const size_t NEED     = 193176576;

  if (ws_size < NEED) { sentinel_kernel<<<1, 1, 0, stream>>>(out); return; }

  u16* xb   = (u16*)(ws + OFF_XB);
  u16* WbT  = (u16*)(ws + OFF_WBT);
  float* Gx = (float*)(ws + OFF_GX);
  u16* hb   = (u16*)(ws + OFF_HB);
  unsigned* hbw = (unsigned*)(ws + OFF_HBW);
  unsigned long long* partials = (unsigned long long*)(ws + OFF_PART);
  unsigned* flags = (unsigned*)(ws + OFF_FLAG);
  float* dump = (float*)(ws + OFF_DUMP);

  prep_kernel<<<2048, 256, 0, stream>>>(inputo, attn, init_hx, xb, hb, hbw, flags);
  transw_kernel<<<dim3(48, 64), 256, 0, stream>>>(W, WbT);
  gemmx_kernel<<<dim3(32, 64), 256, 0, stream>>>(xb, WbT, bias, Gx);

  hipError_t ae = hipFuncSetAttribute((const void*)recur_kernel,
                                      hipFuncAttributeMaxDynamicSharedMemorySize, SMEM_RECUR);
  if (ae != hipSuccess) canary2_kernel<<<1, 1, 0, stream>>>(out);

  // REGULAR launch (not cooperative): co-residency by capacity (128 WGs, 1/CU, 256 CUs).
  recur_kernel<<<dim3(NWG), dim3(256), SMEM_RECUR, stream>>>(
      inputo, WbT, Gx, ln_g, ln_b, init_cx, hb, hbw, partials, flags, dump, out);
  hipError_t le = hipGetLastError();
  if (le != hipSuccess) canary_kernel<<<1, 1, 0, stream>>>(out);
}